// Round 1
// baseline (60.781 us; speedup 1.0000x reference)
//
#include <hip/hip_runtime.h>
#include <cmath>

#define NN 8192
#define MM 64
#define OFF 1e-6f
#define CEPS 1e-8f

// ---------------- Kernel 1: betaK scores -------------------------------------
// grid = B*32 blocks, 256 threads. Each block does 256 rows of one batch.
// 16-lane group per row: float4/lane covers the 64-float row contiguously.
__global__ __launch_bounds__(256) void ntm_scores(
    const float* __restrict__ memory, const float* __restrict__ k_t,
    const float* __restrict__ beta_t, float* __restrict__ out)
{
    const int blocksPerBatch = 32;
    const int rowsPerBlock = NN / blocksPerBatch;      // 256
    const int b = blockIdx.x / blocksPerBatch;
    const int rowBase = (blockIdx.x % blocksPerBatch) * rowsPerBlock;
    const int tid = threadIdx.x;
    const int lane16 = tid & 15;
    const int group = tid >> 4;                        // 0..15

    float4 kv = *(const float4*)(k_t + b * MM + lane16 * 4);
    kv.x += OFF; kv.y += OFF; kv.z += OFF; kv.w += OFF;
    float bn = kv.x*kv.x + kv.y*kv.y + kv.z*kv.z + kv.w*kv.w;
    #pragma unroll
    for (int m = 1; m <= 8; m <<= 1) bn += __shfl_xor(bn, m, 64);
    const float bden = fmaxf(sqrtf(bn), CEPS);
    const float beta = beta_t[b];
    const float* memb = memory + (size_t)b * NN * MM;

    #pragma unroll 4
    for (int r = 0; r < rowsPerBlock / 16; ++r) {
        const int row = rowBase + r * 16 + group;      // 4 consecutive rows/wave
        float4 a = *(const float4*)(memb + (size_t)row * MM + lane16 * 4);
        a.x += OFF; a.y += OFF; a.z += OFF; a.w += OFF;
        float num = a.x*kv.x + a.y*kv.y + a.z*kv.z + a.w*kv.w;
        float nrm = a.x*a.x + a.y*a.y + a.z*a.z + a.w*a.w;
        #pragma unroll
        for (int m = 1; m <= 8; m <<= 1) {
            num += __shfl_xor(num, m, 64);
            nrm += __shfl_xor(nrm, m, 64);
        }
        if (lane16 == 0) {
            const float K = num / (fmaxf(sqrtf(nrm), CEPS) * bden);
            out[(size_t)b * NN + row] = beta * K;
        }
    }
}

// ---------------- Kernel 2: softmax + blend + conv + pow + sum ---------------
__device__ __forceinline__ float blockReduce(float x, bool isMax, float* red) {
    #pragma unroll
    for (int m = 32; m >= 1; m >>= 1) {
        const float o = __shfl_xor(x, m, 64);
        x = isMax ? fmaxf(x, o) : (x + o);
    }
    const int wave = threadIdx.x >> 6;
    const int lane = threadIdx.x & 63;
    __syncthreads();                       // protect red[] from previous use
    if (lane == 0) red[wave] = x;
    __syncthreads();
    if (threadIdx.x < 64) {
        float y = (threadIdx.x < 16) ? red[threadIdx.x] : (isMax ? -3.4e38f : 0.f);
        #pragma unroll
        for (int m = 8; m >= 1; m >>= 1) {
            const float o = __shfl_xor(y, m, 64);
            y = isMax ? fmaxf(y, o) : (y + o);
        }
        if (threadIdx.x == 0) red[0] = y;
    }
    __syncthreads();
    return red[0];
}

__global__ __launch_bounds__(1024) void ntm_finalize(
    const float* __restrict__ g_t, const float* __restrict__ s_t,
    const float* __restrict__ gamma_t, const float* __restrict__ w_prev,
    float* __restrict__ io)
{
    __shared__ float sh[NN];               // 32 KB: w_g row
    __shared__ float red[16];
    const int b = blockIdx.x;
    const int tid = threadIdx.x;
    const size_t base = (size_t)b * NN;

    // load betaK (written by kernel 1 into d_out)
    float v[8];
    float lmax = -3.4e38f;
    #pragma unroll
    for (int k = 0; k < 8; ++k) {
        v[k] = io[base + tid + k * 1024];
        lmax = fmaxf(lmax, v[k]);
    }
    const float m_ = blockReduce(lmax, true, red);

    float ev[8];
    float lsum = 0.f;
    #pragma unroll
    for (int k = 0; k < 8; ++k) { ev[k] = expf(v[k] - m_); lsum += ev[k]; }
    const float Z = blockReduce(lsum, false, red);

    const float g = g_t[b];
    const float gamma = gamma_t[b];
    const float s0 = s_t[b * 3 + 0], s1 = s_t[b * 3 + 1], s2 = s_t[b * 3 + 2];
    const float gz = g / Z;
    const float omg = 1.f - g;

    #pragma unroll
    for (int k = 0; k < 8; ++k) {
        const int i = tid + k * 1024;
        sh[i] = ev[k] * gz + omg * w_prev[base + i];   // w_g
    }
    __syncthreads();

    float wsum = 0.f;
    #pragma unroll
    for (int k = 0; k < 8; ++k) {
        const int i = tid + k * 1024;
        const float wt = s0 * sh[(i + NN - 1) & (NN - 1)]
                       + s1 * sh[i]
                       + s2 * sh[(i + 1) & (NN - 1)];
        wsum += powf(wt, gamma);
    }
    const float total = blockReduce(wsum, false, red) + OFF;

    #pragma unroll
    for (int k = 0; k < 8; ++k) io[base + tid + k * 1024] = total;
}

// ---------------- launch -----------------------------------------------------
extern "C" void kernel_launch(void* const* d_in, const int* in_sizes, int n_in,
                              void* d_out, int out_size, void* d_ws, size_t ws_size,
                              hipStream_t stream) {
    const float* memory = (const float*)d_in[0];
    const float* k_t    = (const float*)d_in[1];
    const float* beta_t = (const float*)d_in[2];
    const float* g_t    = (const float*)d_in[3];
    const float* s_t    = (const float*)d_in[4];
    const float* gamma_t= (const float*)d_in[5];
    const float* w_prev = (const float*)d_in[6];
    float* out = (float*)d_out;
    const int B = in_sizes[2];             // beta_t element count = 128

    ntm_scores<<<B * 32, 256, 0, stream>>>(memory, k_t, beta_t, out);
    ntm_finalize<<<B, 1024, 0, stream>>>(g_t, s_t, gamma_t, w_prev, out);
}

// Round 3
// 51.759 us; speedup vs baseline: 1.1743x; 1.1743x over previous
//
#include <hip/hip_runtime.h>
#include <cmath>

#define NN 8192
#define MM 64
#define OFF 1e-6f
#define CEPS 1e-8f

// ---------------- Kernel 1: betaK scores -------------------------------------
// grid = B*32 blocks, 256 threads. Each block does 256 rows of one batch.
// 8-lane group per row; each lane holds 8 floats (two float4s: first/second
// half of the 64-float row). Both load instructions are 128B-contiguous per
// group (1KB per wave). Reduction: 3 shuffle levels (masks 1,2,4).
__global__ __launch_bounds__(256) void ntm_scores(
    const float* __restrict__ memory, const float* __restrict__ k_t,
    const float* __restrict__ beta_t, float* __restrict__ out)
{
    const int blocksPerBatch = 32;
    const int rowsPerBlock = NN / blocksPerBatch;      // 256
    const int b = blockIdx.x / blocksPerBatch;
    const int rowBase = (blockIdx.x % blocksPerBatch) * rowsPerBlock;
    const int tid = threadIdx.x;
    const int lane8 = tid & 7;
    const int group = tid >> 3;                        // 0..31

    // k (+OFF): lane holds elems [lane8*4, +4) and [32+lane8*4, +4)
    float4 kd0 = *(const float4*)(k_t + b * MM + lane8 * 4);
    float4 kd1 = *(const float4*)(k_t + b * MM + 32 + lane8 * 4);
    kd0.x += OFF; kd0.y += OFF; kd0.z += OFF; kd0.w += OFF;
    kd1.x += OFF; kd1.y += OFF; kd1.z += OFF; kd1.w += OFF;
    float bn = kd0.x*kd0.x + kd0.y*kd0.y + kd0.z*kd0.z + kd0.w*kd0.w
             + kd1.x*kd1.x + kd1.y*kd1.y + kd1.z*kd1.z + kd1.w*kd1.w;
    #pragma unroll
    for (int m = 1; m <= 4; m <<= 1) bn += __shfl_xor(bn, m, 64);
    const float bden = fmaxf(sqrtf(bn), CEPS);
    const float beta = beta_t[b];
    const float* memb = memory + (size_t)b * NN * MM;

    #pragma unroll 2
    for (int it = 0; it < rowsPerBlock / 32; ++it) {   // 8 iterations
        const int row = rowBase + it * 32 + group;
        const float* rowp = memb + (size_t)row * MM;
        float4 a0 = *(const float4*)(rowp + lane8 * 4);
        float4 a1 = *(const float4*)(rowp + 32 + lane8 * 4);
        a0.x += OFF; a0.y += OFF; a0.z += OFF; a0.w += OFF;
        a1.x += OFF; a1.y += OFF; a1.z += OFF; a1.w += OFF;
        float num = a0.x*kd0.x + a0.y*kd0.y + a0.z*kd0.z + a0.w*kd0.w
                  + a1.x*kd1.x + a1.y*kd1.y + a1.z*kd1.z + a1.w*kd1.w;
        float nrm = a0.x*a0.x + a0.y*a0.y + a0.z*a0.z + a0.w*a0.w
                  + a1.x*a1.x + a1.y*a1.y + a1.z*a1.z + a1.w*a1.w;
        #pragma unroll
        for (int m = 1; m <= 4; m <<= 1) {
            num += __shfl_xor(num, m, 64);
            nrm += __shfl_xor(nrm, m, 64);
        }
        if (lane8 == 0) {
            const float K = num / (fmaxf(sqrtf(nrm), CEPS) * bden);
            out[(size_t)b * NN + row] = beta * K;
        }
    }
}

// ---------------- Kernel 2: softmax + blend + conv + pow + sum ---------------
__device__ __forceinline__ float blockReduceSum(float x, float* red) {
    #pragma unroll
    for (int m = 32; m >= 1; m >>= 1) x += __shfl_xor(x, m, 64);
    const int wave = threadIdx.x >> 6;
    const int lane = threadIdx.x & 63;
    __syncthreads();                       // protect red[] from previous use
    if (lane == 0) red[wave] = x;
    __syncthreads();
    if (threadIdx.x < 64) {
        float y = (threadIdx.x < 16) ? red[threadIdx.x] : 0.f;
        #pragma unroll
        for (int m = 8; m >= 1; m >>= 1) y += __shfl_xor(y, m, 64);
        if (threadIdx.x == 0) red[0] = y;
    }
    __syncthreads();
    return red[0];
}

__global__ __launch_bounds__(1024) void ntm_finalize(
    const float* __restrict__ g_t, const float* __restrict__ s_t,
    const float* __restrict__ gamma_t, const float* __restrict__ w_prev,
    float* __restrict__ io)
{
    __shared__ float sh[NN];               // 32 KB: w_g row
    __shared__ float red[16];
    const int b = blockIdx.x;
    const int tid = threadIdx.x;
    const size_t base = (size_t)b * NN;

    // betaK in [-5,5] (beta<=5, |cos|<=1+eps): exp is safe without max-sub.
    float ev[8];
    float lsum = 0.f;
    #pragma unroll
    for (int k = 0; k < 8; ++k) {
        ev[k] = __expf(io[base + tid + k * 1024]);
        lsum += ev[k];
    }
    const float Z = blockReduceSum(lsum, red);

    const float g = g_t[b];
    const float gamma = gamma_t[b];
    const float s0 = s_t[b * 3 + 0], s1 = s_t[b * 3 + 1], s2 = s_t[b * 3 + 2];
    const float gz = g / Z;
    const float omg = 1.f - g;

    #pragma unroll
    for (int k = 0; k < 8; ++k) {
        const int i = tid + k * 1024;
        sh[i] = ev[k] * gz + omg * w_prev[base + i];   // w_g (>0)
    }
    __syncthreads();

    float wsum = 0.f;
    #pragma unroll
    for (int k = 0; k < 8; ++k) {
        const int i = tid + k * 1024;
        const float wt = s0 * sh[(i + NN - 1) & (NN - 1)]
                       + s1 * sh[i]
                       + s2 * sh[(i + 1) & (NN - 1)];
        wsum += exp2f(gamma * __log2f(wt));            // wt > 0 always
    }
    const float total = blockReduceSum(wsum, red) + OFF;

    #pragma unroll
    for (int k = 0; k < 8; ++k) io[base + tid + k * 1024] = total;
}

// ---------------- launch -----------------------------------------------------
extern "C" void kernel_launch(void* const* d_in, const int* in_sizes, int n_in,
                              void* d_out, int out_size, void* d_ws, size_t ws_size,
                              hipStream_t stream) {
    const float* memory = (const float*)d_in[0];
    const float* k_t    = (const float*)d_in[1];
    const float* beta_t = (const float*)d_in[2];
    const float* g_t    = (const float*)d_in[3];
    const float* s_t    = (const float*)d_in[4];
    const float* gamma_t= (const float*)d_in[5];
    const float* w_prev = (const float*)d_in[6];
    float* out = (float*)d_out;
    const int B = in_sizes[2];             // beta_t element count = 128

    ntm_scores<<<B * 32, 256, 0, stream>>>(memory, k_t, beta_t, out);
    ntm_finalize<<<B, 1024, 0, stream>>>(g_t, s_t, gamma_t, w_prev, out);
}